// Round 12
// baseline (682.371 us; speedup 1.0000x reference)
//
#include <hip/hip_runtime.h>
#include <hip/hip_bf16.h>
#include <cstdint>
#include <cstddef>

#define NN 4096
#define NE 65536
#define HD 256

typedef __attribute__((ext_vector_type(4))) float f32x4;
typedef __attribute__((ext_vector_type(8))) __bf16 bf16x8;

// fast silu: v * rcp(1 + exp2(-log2e * v))
static __device__ __forceinline__ float silu_f(float v) {
  float e = __builtin_amdgcn_exp2f(v * -1.442695040888963f);
  return v * __builtin_amdgcn_rcpf(1.f + e);
}

// ---------------- weight transpose/convert: f32 [K,N] -> bf16 [N,K] ----------
struct TJob { const float* src; __bf16* dst; int K; int N; };
struct TJobs { TJob j[39]; };

__global__ __launch_bounds__(256) void k_transpose(TJobs jobs) {
  TJob jb = jobs.j[blockIdx.z];
  int k0 = blockIdx.x << 5, n0 = blockIdx.y << 5;
  if (k0 >= jb.K || n0 >= jb.N) return;
  __shared__ float t[32][33];
  int tx = threadIdx.x & 31, ty = threadIdx.x >> 5;
#pragma unroll
  for (int r = ty; r < 32; r += 8)
    t[r][tx] = jb.src[(size_t)(k0 + r) * jb.N + n0 + tx];
  __syncthreads();
#pragma unroll
  for (int r = ty; r < 32; r += 8)
    jb.dst[(size_t)(n0 + r) * jb.K + k0 + tx] = (__bf16)t[tx][r];
}

// ---------------- CSR build ----------------
__global__ __launch_bounds__(256) void k_hist(const int* __restrict__ ei, int* __restrict__ cnt) {
  int e = blockIdx.x * 256 + threadIdx.x;
  atomicAdd(&cnt[ei[e]], 1);
}

__global__ __launch_bounds__(1024) void k_scan(const int* __restrict__ cnt, int* __restrict__ offs,
                                               int* __restrict__ cursor) {
  __shared__ int tmp[1024];
  int tid = threadIdx.x;
  int v[4]; int s = 0;
#pragma unroll
  for (int i = 0; i < 4; i++) { v[i] = cnt[tid * 4 + i]; s += v[i]; }
  tmp[tid] = s;
  __syncthreads();
  for (int o = 1; o < 1024; o <<= 1) {
    int t = (tid >= o) ? tmp[tid - o] : 0;
    __syncthreads();
    tmp[tid] += t;
    __syncthreads();
  }
  int base = (tid > 0) ? tmp[tid - 1] : 0;
#pragma unroll
  for (int i = 0; i < 4; i++) {
    offs[tid * 4 + i] = base; cursor[tid * 4 + i] = base; base += v[i];
  }
  if (tid == 1023) offs[4096] = base;
}

__global__ __launch_bounds__(256) void k_scatter(const int* __restrict__ ei, int* __restrict__ cursor,
                                                 int* __restrict__ elist) {
  int e = blockIdx.x * 256 + threadIdx.x;
  int pos = atomicAdd(&cursor[ei[e]], 1);
  elist[pos] = e;
}

// CSR metadata + dist0 + b=0 geometry (radial==dist0, cd from x_in) + xc init
__global__ __launch_bounds__(256) void k_csrinit(const int* __restrict__ elist, const int* __restrict__ ei,
                                                 const float* __restrict__ x, int* __restrict__ rowp,
                                                 int* __restrict__ colp, float* __restrict__ d0p,
                                                 float* __restrict__ radp, float* __restrict__ cdp,
                                                 float* __restrict__ xc) {
  int i = blockIdx.x * 256 + threadIdx.x;
  if (i < NN * 3) xc[i] = x[i];
  int e = elist[i];
  int r = ei[e], c = ei[NE + e];
  rowp[i] = r; colp[i] = c;
  float dx = x[r * 3 + 0] - x[c * 3 + 0];
  float dy = x[r * 3 + 1] - x[c * 3 + 1];
  float dz = x[r * 3 + 2] - x[c * 3 + 2];
  float rad = dx * dx + dy * dy + dz * dz;
  d0p[i] = rad;
  radp[i] = rad;
  float inv = 1.f / (sqrtf(rad + 1e-8f) + 1.f);
  cdp[i * 3 + 0] = dx * inv; cdp[i * 3 + 1] = dy * inv; cdp[i * 3 + 2] = dz * inv;
}

// per-block geometry (radial + coord_diff) in CSR order, from current coords
__global__ __launch_bounds__(256) void k_geo(const int* __restrict__ rowp, const int* __restrict__ colp,
                                             const float* __restrict__ x, float* __restrict__ radp,
                                             float* __restrict__ cdp) {
  int i = blockIdx.x * 256 + threadIdx.x;
  int r = rowp[i], c = colp[i];
  float dx = x[r * 3 + 0] - x[c * 3 + 0];
  float dy = x[r * 3 + 1] - x[c * 3 + 1];
  float dz = x[r * 3 + 2] - x[c * 3 + 2];
  float rad = dx * dx + dy * dy + dz * dz;
  radp[i] = rad;
  float inv = 1.f / (sqrtf(rad + 1e-8f) + 1.f);
  cdp[i * 3 + 0] = dx * inv; cdp[i * 3 + 1] = dy * inv; cdp[i * 3 + 2] = dz * inv;
}

__global__ __launch_bounds__(256) void k_embed(const float* __restrict__ h0, const float* __restrict__ W,
                                               const float* __restrict__ b, float* __restrict__ hf,
                                               __bf16* __restrict__ h16) {
  int n = blockIdx.x, c = threadIdx.x;
  float s = b[c];
#pragma unroll
  for (int i = 0; i < 16; i++) s += h0[n * 16 + i] * W[i * 256 + c];
  hf[(size_t)n * HD + c] = s;
  h16[(size_t)n * HD + c] = (__bf16)s;
}

// bias512 tables: [9][512] = [b1 | zeros] for 6 edge GCLs then 3 coord blocks
__global__ __launch_bounds__(256) void k_mkbias(const float* __restrict__ eb1, const float* __restrict__ cb1,
                                                float* __restrict__ bias512) {
  int i = blockIdx.x * 256 + threadIdx.x;
  int g = i >> 9, r = i & 511;
  float v = 0.f;
  if (r < 256) v = (g < 6) ? eb1[g * 256 + r] : cb1[(g - 6) * 256 + r];
  bias512[i] = v;
}

// seg-sum over CSR (m2p CSR-ordered) -> agg16 = bf16(sum/100)
__global__ __launch_bounds__(256) void k_segsum(const __bf16* __restrict__ m2p, const int* __restrict__ offs,
                                                __bf16* __restrict__ agg16) {
  __shared__ float sd[8][256];
  int n = blockIdx.x, t = threadIdx.x;
  int g = t >> 5, l = t & 31;
  int c0 = l << 3;
  float a[8] = {};
  int ib = offs[n], ie = offs[n + 1];
  for (int i = ib + g; i < ie; i += 8) {
    bf16x8 v = *(const bf16x8*)(m2p + (size_t)i * 256 + c0);
#pragma unroll
    for (int j = 0; j < 8; j++) a[j] += (float)v[j];
  }
#pragma unroll
  for (int j = 0; j < 8; j++) sd[g][c0 + j] = a[j];
  __syncthreads();
  float s = 0.f;
#pragma unroll
  for (int j = 0; j < 8; j++) s += sd[j][t];
  agg16[(size_t)n * 256 + t] = (__bf16)(s * 0.01f);
}

__global__ __launch_bounds__(256) void k_xupd(const float* __restrict__ transp, const int* __restrict__ offs,
                                              float* __restrict__ xc) {
  int n = blockIdx.x * 256 + threadIdx.x;
  if (n >= NN) return;
  float a0 = 0.f, a1 = 0.f, a2 = 0.f;
  int i1 = offs[n + 1];
  for (int i = offs[n]; i < i1; i++) {
    a0 += transp[i * 3 + 0]; a1 += transp[i * 3 + 1]; a2 += transp[i * 3 + 2];
  }
  xc[n * 3 + 0] += a0 * 0.01f;
  xc[n * 3 + 1] += a1 * 0.01f;
  xc[n * 3 + 2] += a2 * 0.01f;
}

// final: out_h = hf@out_w + out_b ; out_x = xc
__global__ __launch_bounds__(256) void k_out(const float* __restrict__ hf, const float* __restrict__ W,
                                             const float* __restrict__ b, const float* __restrict__ xc,
                                             float* __restrict__ out) {
  int t = blockIdx.x * 256 + threadIdx.x;
  if (blockIdx.x < 256) {
    int n = t >> 4, j = t & 15;
    float s = b[j];
    for (int c = 0; c < 256; c++) s += hf[(size_t)n * HD + c] * W[c * 16 + j];
    out[n * 16 + j] = s;
  } else {
    int i = t - NN * 16;
    if (i < NN * 3) out[NN * 16 + i] = xc[i];
  }
}

// ---------------- edge-MLP layer 1 (CSR-ordered, streaming) ----------------
// m1p[i][k] = silu(P[rowp[i]][k] + Q[colp[i]][k] + rad*w1r[k] + d0*w1d[k])   (b1 folded in PQ)
// thread: edge = blk*32 + (tid>>3), 32 elems at (tid&7)*32.
__global__ __launch_bounds__(256) void k_edge1(
    const __bf16* __restrict__ PQ, const int* __restrict__ rowp, const int* __restrict__ colp,
    const float* __restrict__ radp, const float* __restrict__ d0p,
    const float* __restrict__ w1r, const float* __restrict__ w1d,
    __bf16* __restrict__ m1p) {
  __shared__ float wr[256], wd[256];
  int tid = threadIdx.x;
  wr[tid] = w1r[tid];
  wd[tid] = w1d[tid];
  __syncthreads();
  int e = blockIdx.x * 32 + (tid >> 3);
  int k0 = (tid & 7) * 32;
  const __bf16* P = PQ + (size_t)rowp[e] * 512 + k0;
  const __bf16* Q = PQ + (size_t)colp[e] * 512 + 256 + k0;
  const float rad = radp[e], d0 = d0p[e];
#pragma unroll
  for (int q = 0; q < 4; q++) {
    bf16x8 pv = *(const bf16x8*)(P + q * 8);
    bf16x8 qv = *(const bf16x8*)(Q + q * 8);
    bf16x8 o;
#pragma unroll
    for (int j = 0; j < 8; j++) {
      int k = k0 + q * 8 + j;
      o[j] = (__bf16)silu_f((float)pv[j] + (float)qv[j] + rad * wr[k] + d0 * wd[k]);
    }
    *(bf16x8*)(m1p + (size_t)e * 256 + k0 + q * 8) = o;
  }
}

// ---------------- B-stationary GEMM: m2 = epi(m1p @ W2^T + b2) ----------------
// Block = 4 waves, 128 CSR-ordered edges (8 chunks of 16). Wave w owns cols [w*64, w*64+64).
// B (64 cols x K=256) lives in 128 VGPRs per wave, loaded once. A streamed from m1p.
// No block barriers in EPI0 (wave-private LDS restage for coalesced stores).
// EPI 0: m2p[i][col] = silu(out + b2)
// EPI 1: trans[i] = cdp[i] * sum_col(silu(out+b2)*w3[col])   (block LDS reduce)
template <int EPI>
__global__ __launch_bounds__(256, 2) void k_bgemm(
    const __bf16* __restrict__ m1p, const __bf16* __restrict__ Bt,
    const float* __restrict__ b2, const float* __restrict__ w3,
    const float* __restrict__ cdp, __bf16* __restrict__ m2p, float* __restrict__ transp) {
  __shared__ float sb2[256];
  __shared__ float sw3[256];
  __shared__ __bf16 ep[4][16 * 72];   // wave-private restage, stride 72 (bank-spread)
  __shared__ float reds[4][16];
  const int tid = threadIdx.x;
  const int lane = tid & 63;
  const int w = tid >> 6;
  const int l15 = lane & 15;
  const int kg = lane >> 4;
  const int colbase = w * 64;
  sb2[tid] = b2[tid];
  if (EPI == 1) sw3[tid] = w3[tid];
  __syncthreads();

  // B prologue: 64 cols x 256 k in registers
  bf16x8 breg[4][8];
#pragma unroll
  for (int fn = 0; fn < 4; fn++)
#pragma unroll
    for (int ks = 0; ks < 8; ks++)
      breg[fn][ks] = *(const bf16x8*)(Bt + (size_t)(colbase + fn * 16 + l15) * 256 + ks * 32 + kg * 8);

  const int E0 = blockIdx.x * 128;
  for (int c = 0; c < 8; c++) {
    const int e0 = E0 + c * 16;
    bf16x8 av[8];
#pragma unroll
    for (int ks = 0; ks < 8; ks++)
      av[ks] = *(const bf16x8*)(m1p + (size_t)(e0 + l15) * 256 + ks * 32 + kg * 8);
    f32x4 acc[4] = {};
#pragma unroll
    for (int ks = 0; ks < 8; ks++)
#pragma unroll
      for (int fn = 0; fn < 4; fn++)
        acc[fn] = __builtin_amdgcn_mfma_f32_16x16x32_bf16(av[ks], breg[fn][ks], acc[fn], 0, 0, 0);

    if (EPI == 0) {
      // wave-private restage -> coalesced stores (no block barrier needed)
#pragma unroll
      for (int fn = 0; fn < 4; fn++) {
        int col = colbase + fn * 16 + l15;
        float bv = sb2[col];
#pragma unroll
        for (int j = 0; j < 4; j++)
          ep[w][(kg * 4 + j) * 72 + fn * 16 + l15] = (__bf16)silu_f(acc[fn][j] + bv);
      }
#pragma unroll
      for (int p = 0; p < 2; p++) {
        int rr = p * 8 + (lane >> 3);
        int gg = lane & 7;
        uint4 v = *(const uint4*)&ep[w][rr * 72 + gg * 8];
        *(uint4*)(m2p + (size_t)(e0 + rr) * 256 + colbase + gg * 8) = v;
      }
    } else {
      float s[4] = {0.f, 0.f, 0.f, 0.f};
#pragma unroll
      for (int fn = 0; fn < 4; fn++) {
        int col = colbase + fn * 16 + l15;
        float bv = sb2[col], wv = sw3[col];
#pragma unroll
        for (int j = 0; j < 4; j++)
          s[j] += silu_f(acc[fn][j] + bv) * wv;
      }
#pragma unroll
      for (int off = 1; off < 16; off <<= 1)
#pragma unroll
        for (int j = 0; j < 4; j++)
          s[j] += __shfl_xor(s[j], off, 64);
      if (l15 == 0) {
#pragma unroll
        for (int j = 0; j < 4; j++)
          reds[w][kg * 4 + j] = s[j];
      }
      __syncthreads();
      if (tid < 16) {
        float sv = reds[0][tid] + reds[1][tid] + reds[2][tid] + reds[3][tid];
        size_t i = (size_t)e0 + tid;
        transp[i * 3 + 0] = cdp[i * 3 + 0] * sv;
        transp[i * 3 + 1] = cdp[i * 3 + 1] * sv;
        transp[i * 3 + 2] = cdp[i * 3 + 2] * sv;
      }
      __syncthreads();
    }
  }
}

// ---------------- 64x64 MFMA GEMM, 2-phase double-buffered ----------------
// C = epi(A[M,K] @ Bt[N,K]^T + bias).
// SPLIT=1: logical K=512, A-rows = [A(256) || A2(256)], both row-stride 256.
// EPI: 1 silu->bf16, 2 residual f32+=v & bf16 out, 5 bias+bf16
template <int EPI, int SPLIT>
__global__ __launch_bounds__(256) void k_gemm64(const __bf16* __restrict__ A, const __bf16* __restrict__ A2,
                                                const __bf16* __restrict__ Bt,
                                                const float* __restrict__ bias, __bf16* __restrict__ outb,
                                                float* __restrict__ outf, int M, int N, int K) {
  constexpr int BM = 64, BN = 64, BK = 64;
  __shared__ __bf16 As[2][BM * BK];
  __shared__ __bf16 Bs[2][BN * BK];
  const int tid = threadIdx.x;
  const int lane = tid & 63;
  const int wave = tid >> 6;
  const int wm = wave >> 1, wn = wave & 1;   // wave tile 32x32
  const size_t m0 = (size_t)blockIdx.x * BM;
  const size_t n0 = (size_t)blockIdx.y * BN;
  const int r0 = tid >> 3, g0 = tid & 7;
  const int gs0 = (g0 ^ (r0 & 7)) << 3;
  const int Astride = SPLIT ? 256 : K;

  f32x4 acc[2][2] = {};
  const int NT = K >> 6;

  {  // prologue: tile 0 (always from A)
    uint4 a0 = *(const uint4*)(A + (m0 + r0) * Astride + g0 * 8);
    uint4 a1 = *(const uint4*)(A + (m0 + r0 + 32) * Astride + g0 * 8);
    uint4 b0 = *(const uint4*)(Bt + (n0 + r0) * K + g0 * 8);
    uint4 b1 = *(const uint4*)(Bt + (n0 + r0 + 32) * K + g0 * 8);
    *(uint4*)&As[0][r0 * BK + gs0] = a0;
    *(uint4*)&As[0][(r0 + 32) * BK + gs0] = a1;
    *(uint4*)&Bs[0][r0 * BK + gs0] = b0;
    *(uint4*)&Bs[0][(r0 + 32) * BK + gs0] = b1;
  }
  __syncthreads();

  int buf = 0;
  for (int t = 0; t < NT; ++t) {
    const bool has = (t + 1 < NT);
    uint4 a0, a1, b0, b1;
    if (has) {
      int kt = (t + 1) << 6;
      const __bf16* Ab;
      int ko;
      if (SPLIT) { Ab = (kt < 256) ? A : A2; ko = kt & 255; }
      else       { Ab = A; ko = kt; }
      a0 = *(const uint4*)(Ab + (m0 + r0) * Astride + ko + g0 * 8);
      a1 = *(const uint4*)(Ab + (m0 + r0 + 32) * Astride + ko + g0 * 8);
      b0 = *(const uint4*)(Bt + (n0 + r0) * K + kt + g0 * 8);
      b1 = *(const uint4*)(Bt + (n0 + r0 + 32) * K + kt + g0 * 8);
    }
#pragma unroll
    for (int ks = 0; ks < BK; ks += 32) {
      const int kg = (ks >> 3) + (lane >> 4);
      bf16x8 af[2], bfv[2];
#pragma unroll
      for (int fm = 0; fm < 2; fm++) {
        int r = wm * 32 + fm * 16 + (lane & 15);
        af[fm] = *(const bf16x8*)&As[buf][r * BK + ((kg ^ (r & 7)) << 3)];
      }
#pragma unroll
      for (int fn = 0; fn < 2; fn++) {
        int r = wn * 32 + fn * 16 + (lane & 15);
        bfv[fn] = *(const bf16x8*)&Bs[buf][r * BK + ((kg ^ (r & 7)) << 3)];
      }
#pragma unroll
      for (int fm = 0; fm < 2; fm++)
#pragma unroll
        for (int fn = 0; fn < 2; fn++)
          acc[fm][fn] = __builtin_amdgcn_mfma_f32_16x16x32_bf16(af[fm], bfv[fn], acc[fm][fn], 0, 0, 0);
    }
    if (has) {
      *(uint4*)&As[buf ^ 1][r0 * BK + gs0] = a0;
      *(uint4*)&As[buf ^ 1][(r0 + 32) * BK + gs0] = a1;
      *(uint4*)&Bs[buf ^ 1][r0 * BK + gs0] = b0;
      *(uint4*)&Bs[buf ^ 1][(r0 + 32) * BK + gs0] = b1;
    }
    __syncthreads();
    buf ^= 1;
  }

#pragma unroll
  for (int fm = 0; fm < 2; fm++) {
#pragma unroll
    for (int fn = 0; fn < 2; fn++) {
      const size_t col = n0 + wn * 32 + fn * 16 + (lane & 15);
      float bv = bias[col];
#pragma unroll
      for (int j = 0; j < 4; j++) {
        size_t row = m0 + wm * 32 + fm * 16 + ((lane >> 4) << 2) + j;
        size_t idx = row * (size_t)N + col;
        float v = acc[fm][fn][j] + bv;
        if (EPI == 1) {
          outb[idx] = (__bf16)silu_f(v);
        } else if (EPI == 2) {
          float nh = outf[idx] + v;
          outf[idx] = nh;
          outb[idx] = (__bf16)nh;
        } else {
          outb[idx] = (__bf16)v;
        }
      }
    }
  }
}

// ---------------- host ----------------
extern "C" void kernel_launch(void* const* d_in, const int* in_sizes, int n_in,
                              void* d_out, int out_size, void* d_ws, size_t ws_size,
                              hipStream_t stream) {
  const float* h_in    = (const float*)d_in[0];
  const float* x_in    = (const float*)d_in[1];
  const int*   ei      = (const int*)d_in[2];
  const float* emb_w   = (const float*)d_in[3];
  const float* emb_b   = (const float*)d_in[4];
  const float* out_w   = (const float*)d_in[5];
  const float* out_b   = (const float*)d_in[6];
  const float* edge_w1 = (const float*)d_in[7];
  const float* edge_b1 = (const float*)d_in[8];
  const float* edge_w2 = (const float*)d_in[9];
  const float* edge_b2 = (const float*)d_in[10];
  const float* node_w1 = (const float*)d_in[11];
  const float* node_b1 = (const float*)d_in[12];
  const float* node_w2 = (const float*)d_in[13];
  const float* node_b2 = (const float*)d_in[14];
  const float* coord_w1 = (const float*)d_in[15];
  const float* coord_b1 = (const float*)d_in[16];
  const float* coord_w2 = (const float*)d_in[17];
  const float* coord_b2 = (const float*)d_in[18];
  const float* coord_w3 = (const float*)d_in[19];

  char* p = (char*)d_ws;
  auto alloc = [&](size_t bytes) -> void* {
    void* r = (void*)p;
    p += (bytes + 255) & ~(size_t)255;
    return r;
  };
  __bf16* e1T  = (__bf16*)alloc((size_t)6 * 512 * 256 * 2);
  __bf16* e2T  = (__bf16*)alloc((size_t)6 * 256 * 256 * 2);
  __bf16* n1T  = (__bf16*)alloc((size_t)6 * 256 * 512 * 2);
  __bf16* n2T  = (__bf16*)alloc((size_t)6 * 256 * 256 * 2);
  __bf16* c1T  = (__bf16*)alloc((size_t)3 * 512 * 256 * 2);
  __bf16* c2T  = (__bf16*)alloc((size_t)3 * 256 * 256 * 2);
  __bf16* h16  = (__bf16*)alloc((size_t)NN * HD * 2);
  __bf16* PQ16 = (__bf16*)alloc((size_t)NN * 512 * 2);
  __bf16* m1p  = (__bf16*)alloc((size_t)NE * HD * 2);
  __bf16* m2p  = (__bf16*)alloc((size_t)NE * HD * 2);
  __bf16* agg16 = (__bf16*)alloc((size_t)NN * HD * 2);
  __bf16* u    = (__bf16*)alloc((size_t)NN * HD * 2);
  float* hf    = (float*)alloc((size_t)NN * HD * 4);
  float* xc    = (float*)alloc((size_t)NN * 3 * 4);
  float* d0p   = (float*)alloc((size_t)NE * 4);
  float* radp  = (float*)alloc((size_t)NE * 4);
  float* cdp   = (float*)alloc((size_t)NE * 3 * 4);
  float* transp = (float*)alloc((size_t)NE * 3 * 4);
  float* bias512 = (float*)alloc((size_t)9 * 512 * 4);
  int* cnt     = (int*)alloc((size_t)NN * 4);
  int* offs    = (int*)alloc((size_t)(NN + 1) * 4);
  int* cursor  = (int*)alloc((size_t)NN * 4);
  int* elist   = (int*)alloc((size_t)NE * 4);
  int* rowp    = (int*)alloc((size_t)NE * 4);
  int* colp    = (int*)alloc((size_t)NE * 4);

  TJobs jobs;
  int nj = 0;
  for (int gi = 0; gi < 6; gi++) {
    jobs.j[nj++] = { edge_w1 + (size_t)gi * 514 * 256,             e1T + (size_t)gi * 512 * 256,             256, 256 };
    jobs.j[nj++] = { edge_w1 + (size_t)gi * 514 * 256 + 256 * 256, e1T + (size_t)gi * 512 * 256 + 256 * 256, 256, 256 };
    jobs.j[nj++] = { edge_w2 + (size_t)gi * 256 * 256,             e2T + (size_t)gi * 256 * 256,             256, 256 };
    jobs.j[nj++] = { node_w1 + (size_t)gi * 512 * 256,             n1T + (size_t)gi * 256 * 512,             512, 256 };
    jobs.j[nj++] = { node_w2 + (size_t)gi * 256 * 256,             n2T + (size_t)gi * 256 * 256,             256, 256 };
  }
  for (int b = 0; b < 3; b++) {
    jobs.j[nj++] = { coord_w1 + (size_t)b * 514 * 256,             c1T + (size_t)b * 512 * 256,              256, 256 };
    jobs.j[nj++] = { coord_w1 + (size_t)b * 514 * 256 + 256 * 256, c1T + (size_t)b * 512 * 256 + 256 * 256,  256, 256 };
    jobs.j[nj++] = { coord_w2 + (size_t)b * 256 * 256,             c2T + (size_t)b * 256 * 256,              256, 256 };
  }

  hipMemsetAsync(cnt, 0, (size_t)NN * 4, stream);
  k_transpose<<<dim3(16, 8, 39), 256, 0, stream>>>(jobs);
  k_hist<<<NE / 256, 256, 0, stream>>>(ei, cnt);
  k_scan<<<1, 1024, 0, stream>>>(cnt, offs, cursor);
  k_scatter<<<NE / 256, 256, 0, stream>>>(ei, cursor, elist);
  k_csrinit<<<NE / 256, 256, 0, stream>>>(elist, ei, x_in, rowp, colp, d0p, radp, cdp, xc);
  k_mkbias<<<18, 256, 0, stream>>>(edge_b1, coord_b1, bias512);
  k_embed<<<NN, 256, 0, stream>>>(h_in, emb_w, emb_b, hf, h16);

  int gi = 0;
  for (int b = 0; b < 3; b++) {
    for (int s = 0; s < 2; s++, gi++) {
      const float* w1 = edge_w1 + (size_t)gi * 514 * 256;
      // PQ = h @ [W1a|W1b] + [b1|0]  -> bf16
      k_gemm64<5, 0><<<dim3(64, 8), 256, 0, stream>>>(
          h16, nullptr, e1T + (size_t)gi * 512 * 256, bias512 + gi * 512, PQ16, nullptr, NN, 512, 256);
      k_edge1<<<NE / 32, 256, 0, stream>>>(
          PQ16, rowp, colp, radp, d0p, w1 + 512 * 256, w1 + 513 * 256, m1p);
      k_bgemm<0><<<NE / 128, 256, 0, stream>>>(
          m1p, e2T + (size_t)gi * 256 * 256, edge_b2 + gi * 256, nullptr, nullptr, m2p, nullptr);
      k_segsum<<<NN, 256, 0, stream>>>(m2p, offs, agg16);
      k_gemm64<1, 1><<<dim3(64, 4), 256, 0, stream>>>(
          h16, agg16, n1T + (size_t)gi * 256 * 512, node_b1 + gi * 256, u, nullptr, NN, 256, 512);
      k_gemm64<2, 0><<<dim3(64, 4), 256, 0, stream>>>(
          u, nullptr, n2T + (size_t)gi * 256 * 256, node_b2 + gi * 256, h16, hf, NN, 256, 256);
    }
    const float* w1c = coord_w1 + (size_t)b * 514 * 256;
    k_gemm64<5, 0><<<dim3(64, 8), 256, 0, stream>>>(
        h16, nullptr, c1T + (size_t)b * 512 * 256, bias512 + (6 + b) * 512, PQ16, nullptr, NN, 512, 256);
    k_edge1<<<NE / 32, 256, 0, stream>>>(
        PQ16, rowp, colp, radp, d0p, w1c + 512 * 256, w1c + 513 * 256, m1p);
    k_bgemm<1><<<NE / 128, 256, 0, stream>>>(
        m1p, c2T + (size_t)b * 256 * 256, coord_b2 + b * 256, coord_w3 + (size_t)b * 256,
        cdp, nullptr, transp);
    k_xupd<<<NN / 256, 256, 0, stream>>>(transp, offs, xc);
    if (b < 2) k_geo<<<NE / 256, 256, 0, stream>>>(rowp, colp, xc, radp, cdp);
  }
  k_out<<<256 + 48, 256, 0, stream>>>(hf, out_w, out_b, xc, (float*)d_out);
}

// Round 13
// 478.997 us; speedup vs baseline: 1.4246x; 1.4246x over previous
//
#include <hip/hip_runtime.h>
#include <hip/hip_bf16.h>
#include <cstdint>
#include <cstddef>

#define NN 4096
#define NE 65536
#define HD 256

typedef __attribute__((ext_vector_type(4))) float f32x4;
typedef __attribute__((ext_vector_type(8))) __bf16 bf16x8;

// fast silu: v * rcp(1 + exp2(-log2e * v))
static __device__ __forceinline__ float silu_f(float v) {
  float e = __builtin_amdgcn_exp2f(v * -1.442695040888963f);
  return v * __builtin_amdgcn_rcpf(1.f + e);
}

// ---------------- weight transpose/convert: f32 [K,N] -> bf16 [N,K] ----------
struct TJob { const float* src; __bf16* dst; int K; int N; };
struct TJobs { TJob j[39]; };

__global__ __launch_bounds__(256) void k_transpose(TJobs jobs) {
  TJob jb = jobs.j[blockIdx.z];
  int k0 = blockIdx.x << 5, n0 = blockIdx.y << 5;
  if (k0 >= jb.K || n0 >= jb.N) return;
  __shared__ float t[32][33];
  int tx = threadIdx.x & 31, ty = threadIdx.x >> 5;
#pragma unroll
  for (int r = ty; r < 32; r += 8)
    t[r][tx] = jb.src[(size_t)(k0 + r) * jb.N + n0 + tx];
  __syncthreads();
#pragma unroll
  for (int r = ty; r < 32; r += 8)
    jb.dst[(size_t)(n0 + r) * jb.K + k0 + tx] = (__bf16)t[tx][r];
}

// ---------------- CSR build ----------------
__global__ __launch_bounds__(256) void k_hist(const int* __restrict__ ei, int* __restrict__ cnt) {
  int e = blockIdx.x * 256 + threadIdx.x;
  atomicAdd(&cnt[ei[e]], 1);
}

__global__ __launch_bounds__(1024) void k_scan(const int* __restrict__ cnt, int* __restrict__ offs,
                                               int* __restrict__ cursor) {
  __shared__ int tmp[1024];
  int tid = threadIdx.x;
  int v[4]; int s = 0;
#pragma unroll
  for (int i = 0; i < 4; i++) { v[i] = cnt[tid * 4 + i]; s += v[i]; }
  tmp[tid] = s;
  __syncthreads();
  for (int o = 1; o < 1024; o <<= 1) {
    int t = (tid >= o) ? tmp[tid - o] : 0;
    __syncthreads();
    tmp[tid] += t;
    __syncthreads();
  }
  int base = (tid > 0) ? tmp[tid - 1] : 0;
#pragma unroll
  for (int i = 0; i < 4; i++) {
    offs[tid * 4 + i] = base; cursor[tid * 4 + i] = base; base += v[i];
  }
  if (tid == 1023) offs[4096] = base;
}

__global__ __launch_bounds__(256) void k_scatter(const int* __restrict__ ei, int* __restrict__ cursor,
                                                 int* __restrict__ elist) {
  int e = blockIdx.x * 256 + threadIdx.x;
  int pos = atomicAdd(&cursor[ei[e]], 1);
  elist[pos] = e;
}

// CSR metadata + dist0 (from initial x) + xc init
__global__ __launch_bounds__(256) void k_csrinit(const int* __restrict__ elist, const int* __restrict__ ei,
                                                 const float* __restrict__ x, int* __restrict__ rowp,
                                                 int* __restrict__ colp, float* __restrict__ d0p,
                                                 float* __restrict__ xc) {
  int i = blockIdx.x * 256 + threadIdx.x;
  if (i < NN * 3) xc[i] = x[i];
  int e = elist[i];
  int r = ei[e], c = ei[NE + e];
  rowp[i] = r; colp[i] = c;
  float dx = x[r * 3 + 0] - x[c * 3 + 0];
  float dy = x[r * 3 + 1] - x[c * 3 + 1];
  float dz = x[r * 3 + 2] - x[c * 3 + 2];
  d0p[i] = dx * dx + dy * dy + dz * dz;
}

// per-block geometry (radial + coord_diff) in CSR order, from current coords
__global__ __launch_bounds__(256) void k_geo(const int* __restrict__ rowp, const int* __restrict__ colp,
                                             const float* __restrict__ x, float* __restrict__ radp,
                                             float* __restrict__ cdp) {
  int i = blockIdx.x * 256 + threadIdx.x;
  int r = rowp[i], c = colp[i];
  float dx = x[r * 3 + 0] - x[c * 3 + 0];
  float dy = x[r * 3 + 1] - x[c * 3 + 1];
  float dz = x[r * 3 + 2] - x[c * 3 + 2];
  float rad = dx * dx + dy * dy + dz * dz;
  radp[i] = rad;
  float inv = 1.f / (sqrtf(rad + 1e-8f) + 1.f);
  cdp[i * 3 + 0] = dx * inv; cdp[i * 3 + 1] = dy * inv; cdp[i * 3 + 2] = dz * inv;
}

__global__ __launch_bounds__(256) void k_embed(const float* __restrict__ h0, const float* __restrict__ W,
                                               const float* __restrict__ b, float* __restrict__ hf,
                                               __bf16* __restrict__ h16) {
  int n = blockIdx.x, c = threadIdx.x;
  float s = b[c];
#pragma unroll
  for (int i = 0; i < 16; i++) s += h0[n * 16 + i] * W[i * 256 + c];
  hf[(size_t)n * HD + c] = s;
  h16[(size_t)n * HD + c] = (__bf16)s;
}

// bias512 tables: [9][512] = [b1 | zeros] for 6 edge GCLs then 3 coord blocks
__global__ __launch_bounds__(256) void k_mkbias(const float* __restrict__ eb1, const float* __restrict__ cb1,
                                                float* __restrict__ bias512) {
  int i = blockIdx.x * 256 + threadIdx.x;
  int g = i >> 9, r = i & 511;
  float v = 0.f;
  if (r < 256) v = (g < 6) ? eb1[g * 256 + r] : cb1[(g - 6) * 256 + r];
  bias512[i] = v;
}

// seg-sum over CSR (m2p CSR-ordered) -> agg16 = bf16(sum/100)
__global__ __launch_bounds__(256) void k_segsum(const __bf16* __restrict__ m2p, const int* __restrict__ offs,
                                                __bf16* __restrict__ agg16) {
  __shared__ float sd[8][256];
  int n = blockIdx.x, t = threadIdx.x;
  int g = t >> 5, l = t & 31;
  int c0 = l << 3;
  float a[8] = {};
  int ib = offs[n], ie = offs[n + 1];
  for (int i = ib + g; i < ie; i += 8) {
    bf16x8 v = *(const bf16x8*)(m2p + (size_t)i * 256 + c0);
#pragma unroll
    for (int j = 0; j < 8; j++) a[j] += (float)v[j];
  }
#pragma unroll
  for (int j = 0; j < 8; j++) sd[g][c0 + j] = a[j];
  __syncthreads();
  float s = 0.f;
#pragma unroll
  for (int j = 0; j < 8; j++) s += sd[j][t];
  agg16[(size_t)n * 256 + t] = (__bf16)(s * 0.01f);
}

__global__ __launch_bounds__(256) void k_xupd(const float* __restrict__ transp, const int* __restrict__ offs,
                                              float* __restrict__ xc) {
  int n = blockIdx.x * 256 + threadIdx.x;
  if (n >= NN) return;
  float a0 = 0.f, a1 = 0.f, a2 = 0.f;
  int i1 = offs[n + 1];
  for (int i = offs[n]; i < i1; i++) {
    a0 += transp[i * 3 + 0]; a1 += transp[i * 3 + 1]; a2 += transp[i * 3 + 2];
  }
  xc[n * 3 + 0] += a0 * 0.01f;
  xc[n * 3 + 1] += a1 * 0.01f;
  xc[n * 3 + 2] += a2 * 0.01f;
}

// final: out_h = hf@out_w + out_b ; out_x = xc
__global__ __launch_bounds__(256) void k_out(const float* __restrict__ hf, const float* __restrict__ W,
                                             const float* __restrict__ b, const float* __restrict__ xc,
                                             float* __restrict__ out) {
  int t = blockIdx.x * 256 + threadIdx.x;
  if (blockIdx.x < 256) {
    int n = t >> 4, j = t & 15;
    float s = b[j];
    for (int c = 0; c < 256; c++) s += hf[(size_t)n * HD + c] * W[c * 16 + j];
    out[n * 16 + j] = s;
  } else {
    int i = t - NN * 16;
    if (i < NN * 3) out[NN * 16 + i] = xc[i];
  }
}

// ---------------- fused edge-block kernel (v4.2 = R8 best: 8 waves, DMA, setprio) -------
// Block = 8 waves = 128 CSR-ordered edges; each wave owns 16 edges, all 256 cols.
// A-fragment per-lane in regs: gather PQ[row]/PQ[col] 16B + silu (b1 pre-folded into PQ).
// B = W2^T staged [2][256][32] in LDS via global_load_lds; 1 barrier per K-step.
// EPI 0: m2p[i][col] = silu(out + b2)  (LDS-restaged coalesced stores)
// EPI 1: trans[i] = cdp[i] * sum_col(silu(out+b2)*w3[col])
template <int EPI>
__global__ __launch_bounds__(512, 4) void k_edgeblk(
    const __bf16* __restrict__ PQ, const int* __restrict__ rowp, const int* __restrict__ colp,
    const float* __restrict__ radp, const float* __restrict__ d0p,
    const float* __restrict__ w1r, const float* __restrict__ w1d,
    const __bf16* __restrict__ Bt, const float* __restrict__ b2,
    __bf16* __restrict__ m2p,
    const float* __restrict__ w3, const float* __restrict__ cdp, float* __restrict__ transp) {
  __shared__ alignas(16) char smem[37888];
  float*  wgt = (float*)smem;                    // w1r,w1d,b2,(w3)
  __bf16* Bs0 = (__bf16*)(smem + 4096);          // [256][32] buffer 0, slot-linear
  __bf16* Bs1 = (__bf16*)(smem + 4096 + 16384);  // buffer 1
  float*  reds = (float*)(smem + 4096);          // EPI1 overlay

  const int tid = threadIdx.x;
  const int lane = tid & 63;
  const int w = tid >> 6;            // wave 0..7
  const int l15 = lane & 15;
  const int kg = lane >> 4;          // k-granule 0..3
  const int R0 = blockIdx.x * 128;
  const int rowg = R0 + w * 16 + l15;

  const __bf16* pBase = PQ + (size_t)rowp[rowg] * 512;
  const __bf16* qBase = PQ + (size_t)colp[rowg] * 512 + 256;
  const float rad = radp[rowg], dd0 = d0p[rowg];

  if (tid < 256) {
    wgt[tid]       = w1r[tid];
    wgt[256 + tid] = w1d[tid];
  } else {
    int t2 = tid - 256;
    wgt[512 + t2] = b2[t2];
    if (EPI == 1) wgt[768 + t2] = w3[t2];
  }

  // B staging: pre-swizzled GLOBAL source + LINEAR LDS dest (DMA)
  int srcOff[2];
#pragma unroll
  for (int q = 0; q < 2; q++) {
    int s = q * 512 + tid;
    int n = s >> 2, g = s & 3;
    srcOff[q] = n * 256 + ((g ^ ((n >> 1) & 3)) << 3);
  }
  const int dstE0 = (0 * 512 + (w << 6)) * 8;
  const int dstE1 = (1 * 512 + (w << 6)) * 8;

  __builtin_amdgcn_global_load_lds((const unsigned int*)(Bt + srcOff[0]),
                                   (unsigned int*)(Bs0 + dstE0), 16, 0, 0);
  __builtin_amdgcn_global_load_lds((const unsigned int*)(Bt + srcOff[1]),
                                   (unsigned int*)(Bs0 + dstE1), 16, 0, 0);
  bf16x8 pvc = *(const bf16x8*)(pBase + kg * 8);
  bf16x8 qvc = *(const bf16x8*)(qBase + kg * 8);
  __syncthreads();

  f32x4 acc[16] = {};

#pragma unroll
  for (int t = 0; t < 8; t++) {
    const __bf16* Bcur = (t & 1) ? Bs1 : Bs0;
    __bf16*       Bnxt = (t & 1) ? Bs0 : Bs1;
    bf16x8 pvn, qvn;
    if (t < 7) {   // DMA next B tile + issue PQ prefetch early
      int kt = (t + 1) * 32;
      __builtin_amdgcn_global_load_lds((const unsigned int*)(Bt + kt + srcOff[0]),
                                       (unsigned int*)(Bnxt + dstE0), 16, 0, 0);
      __builtin_amdgcn_global_load_lds((const unsigned int*)(Bt + kt + srcOff[1]),
                                       (unsigned int*)(Bnxt + dstE1), 16, 0, 0);
      pvn = *(const bf16x8*)(pBase + kt + kg * 8);
      qvn = *(const bf16x8*)(qBase + kt + kg * 8);
    }
    const int k0 = t * 32 + kg * 8;
    f32x4 wr0 = *(const f32x4*)&wgt[k0],       wr1 = *(const f32x4*)&wgt[k0 + 4];
    f32x4 wd0 = *(const f32x4*)&wgt[256 + k0], wd1 = *(const f32x4*)&wgt[256 + k0 + 4];
    bf16x8 af;
#pragma unroll
    for (int j = 0; j < 4; j++)
      af[j] = (__bf16)silu_f((float)pvc[j] + (float)qvc[j] + rad * wr0[j] + dd0 * wd0[j]);
#pragma unroll
    for (int j = 0; j < 4; j++)
      af[4 + j] = (__bf16)silu_f((float)pvc[4 + j] + (float)qvc[4 + j] + rad * wr1[j] + dd0 * wd1[j]);
    __builtin_amdgcn_s_setprio(1);
#pragma unroll
    for (int fn = 0; fn < 16; fn++) {
      int n = fn * 16 + l15;
      bf16x8 bf = *(const bf16x8*)&Bcur[n * 32 + ((kg ^ ((n >> 1) & 3)) << 3)];
      acc[fn] = __builtin_amdgcn_mfma_f32_16x16x32_bf16(af, bf, acc[fn], 0, 0, 0);
    }
    __builtin_amdgcn_s_setprio(0);
    if (t < 7) { pvc = pvn; qvc = qvn; }
    __syncthreads();
  }

  // ---- epilogue ----
  if (EPI == 0) {
    __bf16* ep = (__bf16*)(smem + 4096 + w * 4224);  // [8][264]
#pragma unroll
    for (int p = 0; p < 2; p++) {
      if ((kg >> 1) == p) {
        int rl = (kg & 1) * 4;
#pragma unroll
        for (int fn = 0; fn < 16; fn++) {
          int col = fn * 16 + l15;
          float bv = wgt[512 + col];
#pragma unroll
          for (int j = 0; j < 4; j++)
            ep[(rl + j) * 264 + col] = (__bf16)silu_f(acc[fn][j] + bv);
        }
      }
      __syncthreads();
#pragma unroll
      for (int i = 0; i < 4; i++) {
        int r = i * 2 + (lane >> 5);
        int g = lane & 31;
        uint4 v = *(const uint4*)&ep[r * 264 + g * 8];
        *(uint4*)(m2p + ((size_t)(R0 + w * 16 + p * 8 + r)) * 256 + g * 8) = v;
      }
      __syncthreads();
    }
  } else {
    float s[4] = {0.f, 0.f, 0.f, 0.f};
#pragma unroll
    for (int fn = 0; fn < 16; fn++) {
      int col = fn * 16 + l15;
      float bv = wgt[512 + col], wv = wgt[768 + col];
#pragma unroll
      for (int j = 0; j < 4; j++)
        s[j] += silu_f(acc[fn][j] + bv) * wv;
    }
#pragma unroll
    for (int off = 1; off < 16; off <<= 1)
#pragma unroll
      for (int j = 0; j < 4; j++)
        s[j] += __shfl_xor(s[j], off, 64);
    __syncthreads();
    if (l15 == 0) {
#pragma unroll
      for (int j = 0; j < 4; j++)
        reds[w * 16 + kg * 4 + j] = s[j];
    }
    __syncthreads();
    if (tid < 128) {
      float sv = reds[tid];
      size_t i = (size_t)R0 + tid;
      transp[i * 3 + 0] = cdp[i * 3 + 0] * sv;
      transp[i * 3 + 1] = cdp[i * 3 + 1] * sv;
      transp[i * 3 + 2] = cdp[i * 3 + 2] * sv;
    }
  }
}

// ---------------- fused node MLP: h += silu([h|agg] @ W1^T + b1) @ W2^T + b2 ----------
// Block = 8 waves, 16 node rows (grid 256). Wave w owns cols [w*32, w*32+32).
// Phase 1: A-frags direct from global (h16 / agg16, L1-hot rows), B direct from L2.
// u tile -> LDS (16 x 264 bf16). One barrier. Phase 2: A from LDS, B from L2, residual out.
__global__ __launch_bounds__(512) void k_nodemlp(
    const __bf16* __restrict__ h16, const __bf16* __restrict__ agg16,
    const __bf16* __restrict__ W1t, const float* __restrict__ b1,
    const __bf16* __restrict__ W2t, const float* __restrict__ b2,
    __bf16* __restrict__ h16o, float* __restrict__ hf) {
  __shared__ __bf16 us[16 * 264];
  const int tid = threadIdx.x;
  const int lane = tid & 63;
  const int w = tid >> 6;          // 0..7
  const int l15 = lane & 15;
  const int kg = lane >> 4;
  const int R0 = blockIdx.x * 16;
  const int colb = w * 32;

  // phase 1: u = silu(ncat @ W1^T + b1), ncat = [h16 | agg16], K=512
  f32x4 acc[2] = {};
#pragma unroll
  for (int ks = 0; ks < 16; ks++) {
    const __bf16* Asrc = (ks < 8)
        ? (h16  + (size_t)(R0 + l15) * 256 + ks * 32 + kg * 8)
        : (agg16 + (size_t)(R0 + l15) * 256 + (ks - 8) * 32 + kg * 8);
    bf16x8 av = *(const bf16x8*)Asrc;
#pragma unroll
    for (int fn = 0; fn < 2; fn++) {
      bf16x8 bv = *(const bf16x8*)(W1t + (size_t)(colb + fn * 16 + l15) * 512 + ks * 32 + kg * 8);
      acc[fn] = __builtin_amdgcn_mfma_f32_16x16x32_bf16(av, bv, acc[fn], 0, 0, 0);
    }
  }
#pragma unroll
  for (int fn = 0; fn < 2; fn++) {
    int col = colb + fn * 16 + l15;
    float bv = b1[col];
#pragma unroll
    for (int j = 0; j < 4; j++)
      us[(kg * 4 + j) * 264 + col] = (__bf16)silu_f(acc[fn][j] + bv);
  }
  __syncthreads();

  // phase 2: h += u @ W2^T + b2  (K=256, A from LDS)
  f32x4 acc2[2] = {};
#pragma unroll
  for (int ks = 0; ks < 8; ks++) {
    bf16x8 av = *(const bf16x8*)&us[l15 * 264 + ks * 32 + kg * 8];
#pragma unroll
    for (int fn = 0; fn < 2; fn++) {
      bf16x8 bv = *(const bf16x8*)(W2t + (size_t)(colb + fn * 16 + l15) * 256 + ks * 32 + kg * 8);
      acc2[fn] = __builtin_amdgcn_mfma_f32_16x16x32_bf16(av, bv, acc2[fn], 0, 0, 0);
    }
  }
#pragma unroll
  for (int fn = 0; fn < 2; fn++) {
    int col = colb + fn * 16 + l15;
    float bv = b2[col];
#pragma unroll
    for (int j = 0; j < 4; j++) {
      size_t idx = (size_t)(R0 + kg * 4 + j) * 256 + col;
      float nh = hf[idx] + acc2[fn][j] + bv;
      hf[idx] = nh;
      h16o[idx] = (__bf16)nh;
    }
  }
}

// ---------------- 64x64 MFMA GEMM, 2-phase double-buffered (PQ path) ----------------
// C[M,N] = A[M,K] @ Bt[N,K]^T + bias -> bf16
__global__ __launch_bounds__(256) void k_gemm64(const __bf16* __restrict__ A,
                                                const __bf16* __restrict__ Bt,
                                                const float* __restrict__ bias,
                                                __bf16* __restrict__ outb, int M, int N, int K) {
  constexpr int BM = 64, BN = 64, BK = 64;
  __shared__ __bf16 As[2][BM * BK];
  __shared__ __bf16 Bs[2][BN * BK];
  const int tid = threadIdx.x;
  const int lane = tid & 63;
  const int wave = tid >> 6;
  const int wm = wave >> 1, wn = wave & 1;
  const size_t m0 = (size_t)blockIdx.x * BM;
  const size_t n0 = (size_t)blockIdx.y * BN;
  const int r0 = tid >> 3, g0 = tid & 7;
  const int gs0 = (g0 ^ (r0 & 7)) << 3;

  f32x4 acc[2][2] = {};
  const int NT = K >> 6;

  {
    uint4 a0 = *(const uint4*)(A + (m0 + r0) * K + g0 * 8);
    uint4 a1 = *(const uint4*)(A + (m0 + r0 + 32) * K + g0 * 8);
    uint4 b0 = *(const uint4*)(Bt + (n0 + r0) * K + g0 * 8);
    uint4 b1 = *(const uint4*)(Bt + (n0 + r0 + 32) * K + g0 * 8);
    *(uint4*)&As[0][r0 * BK + gs0] = a0;
    *(uint4*)&As[0][(r0 + 32) * BK + gs0] = a1;
    *(uint4*)&Bs[0][r0 * BK + gs0] = b0;
    *(uint4*)&Bs[0][(r0 + 32) * BK + gs0] = b1;
  }
  __syncthreads();

  int buf = 0;
  for (int t = 0; t < NT; ++t) {
    const bool has = (t + 1 < NT);
    uint4 a0, a1, b0, b1;
    if (has) {
      int kt = (t + 1) << 6;
      a0 = *(const uint4*)(A + (m0 + r0) * K + kt + g0 * 8);
      a1 = *(const uint4*)(A + (m0 + r0 + 32) * K + kt + g0 * 8);
      b0 = *(const uint4*)(Bt + (n0 + r0) * K + kt + g0 * 8);
      b1 = *(const uint4*)(Bt + (n0 + r0 + 32) * K + kt + g0 * 8);
    }
#pragma unroll
    for (int ks = 0; ks < BK; ks += 32) {
      const int kg = (ks >> 3) + (lane >> 4);
      bf16x8 af[2], bfv[2];
#pragma unroll
      for (int fm = 0; fm < 2; fm++) {
        int r = wm * 32 + fm * 16 + (lane & 15);
        af[fm] = *(const bf16x8*)&As[buf][r * BK + ((kg ^ (r & 7)) << 3)];
      }
#pragma unroll
      for (int fn = 0; fn < 2; fn++) {
        int r = wn * 32 + fn * 16 + (lane & 15);
        bfv[fn] = *(const bf16x8*)&Bs[buf][r * BK + ((kg ^ (r & 7)) << 3)];
      }
#pragma unroll
      for (int fm = 0; fm < 2; fm++)
#pragma unroll
        for (int fn = 0; fn < 2; fn++)
          acc[fm][fn] = __builtin_amdgcn_mfma_f32_16x16x32_bf16(af[fm], bfv[fn], acc[fm][fn], 0, 0, 0);
    }
    if (has) {
      *(uint4*)&As[buf ^ 1][r0 * BK + gs0] = a0;
      *(uint4*)&As[buf ^ 1][(r0 + 32) * BK + gs0] = a1;
      *(uint4*)&Bs[buf ^ 1][r0 * BK + gs0] = b0;
      *(uint4*)&Bs[buf ^ 1][(r0 + 32) * BK + gs0] = b1;
    }
    __syncthreads();
    buf ^= 1;
  }

#pragma unroll
  for (int fm = 0; fm < 2; fm++) {
#pragma unroll
    for (int fn = 0; fn < 2; fn++) {
      const size_t col = n0 + wn * 32 + fn * 16 + (lane & 15);
      float bv = bias[col];
#pragma unroll
      for (int j = 0; j < 4; j++) {
        size_t row = m0 + wm * 32 + fm * 16 + ((lane >> 4) << 2) + j;
        outb[row * (size_t)N + col] = (__bf16)(acc[fm][fn][j] + bv);
      }
    }
  }
}

// ---------------- host ----------------
extern "C" void kernel_launch(void* const* d_in, const int* in_sizes, int n_in,
                              void* d_out, int out_size, void* d_ws, size_t ws_size,
                              hipStream_t stream) {
  const float* h_in    = (const float*)d_in[0];
  const float* x_in    = (const float*)d_in[1];
  const int*   ei      = (const int*)d_in[2];
  const float* emb_w   = (const float*)d_in[3];
  const float* emb_b   = (const float*)d_in[4];
  const float* out_w   = (const float*)d_in[5];
  const float* out_b   = (const float*)d_in[6];
  const float* edge_w1 = (const float*)d_in[7];
  const float* edge_b1 = (const float*)d_in[8];
  const float* edge_w2 = (const float*)d_in[9];
  const float* edge_b2 = (const float*)d_in[10];
  const float* node_w1 = (const float*)d_in[11];
  const float* node_b1 = (const float*)d_in[12];
  const float* node_w2 = (const float*)d_in[13];
  const float* node_b2 = (const float*)d_in[14];
  const float* coord_w1 = (const float*)d_in[15];
  const float* coord_b1 = (const float*)d_in[16];
  const float* coord_w2 = (const float*)d_in[17];
  const float* coord_b2 = (const float*)d_in[18];
  const float* coord_w3 = (const float*)d_in[19];

  char* p = (char*)d_ws;
  auto alloc = [&](size_t bytes) -> void* {
    void* r = (void*)p;
    p += (bytes + 255) & ~(size_t)255;
    return r;
  };
  __bf16* e1T  = (__bf16*)alloc((size_t)6 * 512 * 256 * 2);
  __bf16* e2T  = (__bf16*)alloc((size_t)6 * 256 * 256 * 2);
  __bf16* n1T  = (__bf16*)alloc((size_t)6 * 256 * 512 * 2);
  __bf16* n2T  = (__bf16*)alloc((size_t)6 * 256 * 256 * 2);
  __bf16* c1T  = (__bf16*)alloc((size_t)3 * 512 * 256 * 2);
  __bf16* c2T  = (__bf16*)alloc((size_t)3 * 256 * 256 * 2);
  __bf16* h16  = (__bf16*)alloc((size_t)NN * HD * 2);
  __bf16* PQ16 = (__bf16*)alloc((size_t)NN * 512 * 2);
  __bf16* m2p  = (__bf16*)alloc((size_t)NE * HD * 2);
  __bf16* agg16 = (__bf16*)alloc((size_t)NN * HD * 2);
  float* hf    = (float*)alloc((size_t)NN * HD * 4);
  float* xc    = (float*)alloc((size_t)NN * 3 * 4);
  float* d0p   = (float*)alloc((size_t)NE * 4);
  float* radp  = (float*)alloc((size_t)NE * 4);
  float* cdp   = (float*)alloc((size_t)NE * 3 * 4);
  float* transp = (float*)alloc((size_t)NE * 3 * 4);
  float* bias512 = (float*)alloc((size_t)9 * 512 * 4);
  int* cnt     = (int*)alloc((size_t)NN * 4);
  int* offs    = (int*)alloc((size_t)(NN + 1) * 4);
  int* cursor  = (int*)alloc((size_t)NN * 4);
  int* elist   = (int*)alloc((size_t)NE * 4);
  int* rowp    = (int*)alloc((size_t)NE * 4);
  int* colp    = (int*)alloc((size_t)NE * 4);

  TJobs jobs;
  int nj = 0;
  for (int gi = 0; gi < 6; gi++) {
    jobs.j[nj++] = { edge_w1 + (size_t)gi * 514 * 256,             e1T + (size_t)gi * 512 * 256,             256, 256 };
    jobs.j[nj++] = { edge_w1 + (size_t)gi * 514 * 256 + 256 * 256, e1T + (size_t)gi * 512 * 256 + 256 * 256, 256, 256 };
    jobs.j[nj++] = { edge_w2 + (size_t)gi * 256 * 256,             e2T + (size_t)gi * 256 * 256,             256, 256 };
    jobs.j[nj++] = { node_w1 + (size_t)gi * 512 * 256,             n1T + (size_t)gi * 256 * 512,             512, 256 };
    jobs.j[nj++] = { node_w2 + (size_t)gi * 256 * 256,             n2T + (size_t)gi * 256 * 256,             256, 256 };
  }
  for (int b = 0; b < 3; b++) {
    jobs.j[nj++] = { coord_w1 + (size_t)b * 514 * 256,             c1T + (size_t)b * 512 * 256,              256, 256 };
    jobs.j[nj++] = { coord_w1 + (size_t)b * 514 * 256 + 256 * 256, c1T + (size_t)b * 512 * 256 + 256 * 256,  256, 256 };
    jobs.j[nj++] = { coord_w2 + (size_t)b * 256 * 256,             c2T + (size_t)b * 256 * 256,              256, 256 };
  }

  hipMemsetAsync(cnt, 0, (size_t)NN * 4, stream);
  k_transpose<<<dim3(16, 8, 39), 256, 0, stream>>>(jobs);
  k_hist<<<NE / 256, 256, 0, stream>>>(ei, cnt);
  k_scan<<<1, 1024, 0, stream>>>(cnt, offs, cursor);
  k_scatter<<<NE / 256, 256, 0, stream>>>(ei, cursor, elist);
  k_csrinit<<<NE / 256, 256, 0, stream>>>(elist, ei, x_in, rowp, colp, d0p, xc);
  k_mkbias<<<18, 256, 0, stream>>>(edge_b1, coord_b1, bias512);
  k_embed<<<NN, 256, 0, stream>>>(h_in, emb_w, emb_b, hf, h16);

  int gi = 0;
  for (int b = 0; b < 3; b++) {
    k_geo<<<NE / 256, 256, 0, stream>>>(rowp, colp, xc, radp, cdp);
    for (int s = 0; s < 2; s++, gi++) {
      const float* w1 = edge_w1 + (size_t)gi * 514 * 256;
      // PQ = h @ [W1a|W1b] + [b1|0]  -> bf16
      k_gemm64<<<dim3(64, 8), 256, 0, stream>>>(
          h16, e1T + (size_t)gi * 512 * 256, bias512 + gi * 512, PQ16, NN, 512, 256);
      k_edgeblk<0><<<NE / 128, 512, 0, stream>>>(
          PQ16, rowp, colp, radp, d0p, w1 + 512 * 256, w1 + 513 * 256,
          e2T + (size_t)gi * 256 * 256, edge_b2 + gi * 256, m2p, nullptr, nullptr, nullptr);
      k_segsum<<<NN, 256, 0, stream>>>(m2p, offs, agg16);
      k_nodemlp<<<NN / 16, 512, 0, stream>>>(
          h16, agg16, n1T + (size_t)gi * 256 * 512, node_b1 + gi * 256,
          n2T + (size_t)gi * 256 * 256, node_b2 + gi * 256, h16, hf);
    }
    const float* w1c = coord_w1 + (size_t)b * 514 * 256;
    k_gemm64<<<dim3(64, 8), 256, 0, stream>>>(
        h16, c1T + (size_t)b * 512 * 256, bias512 + (6 + b) * 512, PQ16, NN, 512, 256);
    k_edgeblk<1><<<NE / 128, 512, 0, stream>>>(
        PQ16, rowp, colp, radp, d0p, w1c + 512 * 256, w1c + 513 * 256,
        c2T + (size_t)b * 256 * 256, coord_b2 + b * 256, nullptr,
        coord_w3 + (size_t)b * 256, cdp, transp);
    k_xupd<<<NN / 256, 256, 0, stream>>>(transp, offs, xc);
  }
  k_out<<<256 + 48, 256, 0, stream>>>(hf, out_w, out_b, xc, (float*)d_out);
}

// Round 14
// 458.664 us; speedup vs baseline: 1.4877x; 1.0443x over previous
//
#include <hip/hip_runtime.h>
#include <hip/hip_bf16.h>
#include <cstdint>
#include <cstddef>

#define NN 4096
#define NE 65536
#define HD 256

typedef __attribute__((ext_vector_type(4))) float f32x4;
typedef __attribute__((ext_vector_type(8))) __bf16 bf16x8;

// fast silu: v * rcp(1 + exp2(-log2e * v))
static __device__ __forceinline__ float silu_f(float v) {
  float e = __builtin_amdgcn_exp2f(v * -1.442695040888963f);
  return v * __builtin_amdgcn_rcpf(1.f + e);
}

// ---------------- weight transpose/convert: f32 [K,N] -> bf16 [N,K] ----------
struct TJob { const float* src; __bf16* dst; int K; int N; };
struct TJobs { TJob j[39]; };

__global__ __launch_bounds__(256) void k_transpose(TJobs jobs) {
  TJob jb = jobs.j[blockIdx.z];
  int k0 = blockIdx.x << 5, n0 = blockIdx.y << 5;
  if (k0 >= jb.K || n0 >= jb.N) return;
  __shared__ float t[32][33];
  int tx = threadIdx.x & 31, ty = threadIdx.x >> 5;
#pragma unroll
  for (int r = ty; r < 32; r += 8)
    t[r][tx] = jb.src[(size_t)(k0 + r) * jb.N + n0 + tx];
  __syncthreads();
#pragma unroll
  for (int r = ty; r < 32; r += 8)
    jb.dst[(size_t)(n0 + r) * jb.K + k0 + tx] = (__bf16)t[tx][r];
}

// ---------------- CSR build ----------------
__global__ __launch_bounds__(256) void k_hist(const int* __restrict__ ei, int* __restrict__ cnt) {
  int e = blockIdx.x * 256 + threadIdx.x;
  atomicAdd(&cnt[ei[e]], 1);
}

__global__ __launch_bounds__(1024) void k_scan(const int* __restrict__ cnt, int* __restrict__ offs,
                                               int* __restrict__ cursor) {
  __shared__ int tmp[1024];
  int tid = threadIdx.x;
  int v[4]; int s = 0;
#pragma unroll
  for (int i = 0; i < 4; i++) { v[i] = cnt[tid * 4 + i]; s += v[i]; }
  tmp[tid] = s;
  __syncthreads();
  for (int o = 1; o < 1024; o <<= 1) {
    int t = (tid >= o) ? tmp[tid - o] : 0;
    __syncthreads();
    tmp[tid] += t;
    __syncthreads();
  }
  int base = (tid > 0) ? tmp[tid - 1] : 0;
#pragma unroll
  for (int i = 0; i < 4; i++) {
    offs[tid * 4 + i] = base; cursor[tid * 4 + i] = base; base += v[i];
  }
  if (tid == 1023) offs[4096] = base;
}

__global__ __launch_bounds__(256) void k_scatter(const int* __restrict__ ei, int* __restrict__ cursor,
                                                 int* __restrict__ elist) {
  int e = blockIdx.x * 256 + threadIdx.x;
  int pos = atomicAdd(&cursor[ei[e]], 1);
  elist[pos] = e;
}

// CSR metadata + dist0 (from initial x) + xc init
__global__ __launch_bounds__(256) void k_csrinit(const int* __restrict__ elist, const int* __restrict__ ei,
                                                 const float* __restrict__ x, int* __restrict__ rowp,
                                                 int* __restrict__ colp, float* __restrict__ d0p,
                                                 float* __restrict__ xc) {
  int i = blockIdx.x * 256 + threadIdx.x;
  if (i < NN * 3) xc[i] = x[i];
  int e = elist[i];
  int r = ei[e], c = ei[NE + e];
  rowp[i] = r; colp[i] = c;
  float dx = x[r * 3 + 0] - x[c * 3 + 0];
  float dy = x[r * 3 + 1] - x[c * 3 + 1];
  float dz = x[r * 3 + 2] - x[c * 3 + 2];
  d0p[i] = dx * dx + dy * dy + dz * dz;
}

// per-block geometry (radial + coord_diff) in CSR order, from current coords
__global__ __launch_bounds__(256) void k_geo(const int* __restrict__ rowp, const int* __restrict__ colp,
                                             const float* __restrict__ x, float* __restrict__ radp,
                                             float* __restrict__ cdp) {
  int i = blockIdx.x * 256 + threadIdx.x;
  int r = rowp[i], c = colp[i];
  float dx = x[r * 3 + 0] - x[c * 3 + 0];
  float dy = x[r * 3 + 1] - x[c * 3 + 1];
  float dz = x[r * 3 + 2] - x[c * 3 + 2];
  float rad = dx * dx + dy * dy + dz * dz;
  radp[i] = rad;
  float inv = 1.f / (sqrtf(rad + 1e-8f) + 1.f);
  cdp[i * 3 + 0] = dx * inv; cdp[i * 3 + 1] = dy * inv; cdp[i * 3 + 2] = dz * inv;
}

__global__ __launch_bounds__(256) void k_embed(const float* __restrict__ h0, const float* __restrict__ W,
                                               const float* __restrict__ b, float* __restrict__ hf,
                                               __bf16* __restrict__ h16) {
  int n = blockIdx.x, c = threadIdx.x;
  float s = b[c];
#pragma unroll
  for (int i = 0; i < 16; i++) s += h0[n * 16 + i] * W[i * 256 + c];
  hf[(size_t)n * HD + c] = s;
  h16[(size_t)n * HD + c] = (__bf16)s;
}

// bias512 tables: [9][512] = [b1 | zeros] for 6 edge GCLs then 3 coord blocks
__global__ __launch_bounds__(256) void k_mkbias(const float* __restrict__ eb1, const float* __restrict__ cb1,
                                                float* __restrict__ bias512) {
  int i = blockIdx.x * 256 + threadIdx.x;
  int g = i >> 9, r = i & 511;
  float v = 0.f;
  if (r < 256) v = (g < 6) ? eb1[g * 256 + r] : cb1[(g - 6) * 256 + r];
  bias512[i] = v;
}

// seg-sum over CSR (m2p CSR-ordered) -> agg16 = bf16(sum/100)
__global__ __launch_bounds__(256) void k_segsum(const __bf16* __restrict__ m2p, const int* __restrict__ offs,
                                                __bf16* __restrict__ agg16) {
  __shared__ float sd[8][256];
  int n = blockIdx.x, t = threadIdx.x;
  int g = t >> 5, l = t & 31;
  int c0 = l << 3;
  float a[8] = {};
  int ib = offs[n], ie = offs[n + 1];
  for (int i = ib + g; i < ie; i += 8) {
    bf16x8 v = *(const bf16x8*)(m2p + (size_t)i * 256 + c0);
#pragma unroll
    for (int j = 0; j < 8; j++) a[j] += (float)v[j];
  }
#pragma unroll
  for (int j = 0; j < 8; j++) sd[g][c0 + j] = a[j];
  __syncthreads();
  float s = 0.f;
#pragma unroll
  for (int j = 0; j < 8; j++) s += sd[j][t];
  agg16[(size_t)n * 256 + t] = (__bf16)(s * 0.01f);
}

__global__ __launch_bounds__(256) void k_xupd(const float* __restrict__ transp, const int* __restrict__ offs,
                                              float* __restrict__ xc) {
  int n = blockIdx.x * 256 + threadIdx.x;
  if (n >= NN) return;
  float a0 = 0.f, a1 = 0.f, a2 = 0.f;
  int i1 = offs[n + 1];
  for (int i = offs[n]; i < i1; i++) {
    a0 += transp[i * 3 + 0]; a1 += transp[i * 3 + 1]; a2 += transp[i * 3 + 2];
  }
  xc[n * 3 + 0] += a0 * 0.01f;
  xc[n * 3 + 1] += a1 * 0.01f;
  xc[n * 3 + 2] += a2 * 0.01f;
}

// final: out_h = hf@out_w + out_b ; out_x = xc
__global__ __launch_bounds__(256) void k_out(const float* __restrict__ hf, const float* __restrict__ W,
                                             const float* __restrict__ b, const float* __restrict__ xc,
                                             float* __restrict__ out) {
  int t = blockIdx.x * 256 + threadIdx.x;
  if (blockIdx.x < 256) {
    int n = t >> 4, j = t & 15;
    float s = b[j];
    for (int c = 0; c < 256; c++) s += hf[(size_t)n * HD + c] * W[c * 16 + j];
    out[n * 16 + j] = s;
  } else {
    int i = t - NN * 16;
    if (i < NN * 3) out[NN * 16 + i] = xc[i];
  }
}

// ---------------- fused edge-block kernel (v4.2 = R8 best: 8 waves, global_load_lds, setprio) -------
// Block = 8 waves = 128 CSR-ordered edges; each wave owns 16 edges, all 256 cols.
// A-fragment per-lane in regs: gather PQ[row]/PQ[col] 16B + silu (b1 pre-folded into PQ).
// B = W2^T staged [2][256][32] in LDS via global_load_lds (pre-swizzled global src,
// linear LDS dest), 1 barrier per K-step.
// EPI 0: m2p[i][col] = silu(out + b2)  (LDS-restaged coalesced stores)
// EPI 1: trans[i] = cdp[i] * sum_col(silu(out+b2)*w3[col])
template <int EPI>
__global__ __launch_bounds__(512, 4) void k_edgeblk(
    const __bf16* __restrict__ PQ, const int* __restrict__ rowp, const int* __restrict__ colp,
    const float* __restrict__ radp, const float* __restrict__ d0p,
    const float* __restrict__ w1r, const float* __restrict__ w1d,
    const __bf16* __restrict__ Bt, const float* __restrict__ b2,
    __bf16* __restrict__ m2p,
    const float* __restrict__ w3, const float* __restrict__ cdp, float* __restrict__ transp) {
  __shared__ alignas(16) char smem[37888];
  float*  wgt = (float*)smem;                    // w1r,w1d,b2,(w3)
  __bf16* Bs0 = (__bf16*)(smem + 4096);          // [256][32] buffer 0, slot-linear
  __bf16* Bs1 = (__bf16*)(smem + 4096 + 16384);  // buffer 1
  float*  reds = (float*)(smem + 4096);          // EPI1 overlay

  const int tid = threadIdx.x;
  const int lane = tid & 63;
  const int w = tid >> 6;            // wave 0..7
  const int l15 = lane & 15;
  const int kg = lane >> 4;          // k-granule 0..3
  const int R0 = blockIdx.x * 128;
  const int rowg = R0 + w * 16 + l15;

  const __bf16* pBase = PQ + (size_t)rowp[rowg] * 512;
  const __bf16* qBase = PQ + (size_t)colp[rowg] * 512 + 256;
  const float rad = radp[rowg], dd0 = d0p[rowg];

  if (tid < 256) {
    wgt[tid]       = w1r[tid];
    wgt[256 + tid] = w1d[tid];
  } else {
    int t2 = tid - 256;
    wgt[512 + t2] = b2[t2];
    if (EPI == 1) wgt[768 + t2] = w3[t2];
  }

  // B staging: pre-swizzled GLOBAL source + LINEAR LDS dest (DMA)
  int srcOff[2];
#pragma unroll
  for (int q = 0; q < 2; q++) {
    int s = q * 512 + tid;
    int n = s >> 2, g = s & 3;
    srcOff[q] = n * 256 + ((g ^ ((n >> 1) & 3)) << 3);
  }
  const int dstE0 = (0 * 512 + (w << 6)) * 8;
  const int dstE1 = (1 * 512 + (w << 6)) * 8;

  __builtin_amdgcn_global_load_lds((const unsigned int*)(Bt + srcOff[0]),
                                   (unsigned int*)(Bs0 + dstE0), 16, 0, 0);
  __builtin_amdgcn_global_load_lds((const unsigned int*)(Bt + srcOff[1]),
                                   (unsigned int*)(Bs0 + dstE1), 16, 0, 0);
  bf16x8 pvc = *(const bf16x8*)(pBase + kg * 8);
  bf16x8 qvc = *(const bf16x8*)(qBase + kg * 8);
  __syncthreads();

  f32x4 acc[16] = {};

#pragma unroll
  for (int t = 0; t < 8; t++) {
    const __bf16* Bcur = (t & 1) ? Bs1 : Bs0;
    __bf16*       Bnxt = (t & 1) ? Bs0 : Bs1;
    bf16x8 pvn, qvn;
    if (t < 7) {   // DMA next B tile + issue PQ prefetch early; latency hides under silu+MFMA
      int kt = (t + 1) * 32;
      __builtin_amdgcn_global_load_lds((const unsigned int*)(Bt + kt + srcOff[0]),
                                       (unsigned int*)(Bnxt + dstE0), 16, 0, 0);
      __builtin_amdgcn_global_load_lds((const unsigned int*)(Bt + kt + srcOff[1]),
                                       (unsigned int*)(Bnxt + dstE1), 16, 0, 0);
      pvn = *(const bf16x8*)(pBase + kt + kg * 8);
      qvn = *(const bf16x8*)(qBase + kt + kg * 8);
    }
    // silu -> A fragment (row = l15's edge, k = t*32 + kg*8 + j)
    const int k0 = t * 32 + kg * 8;
    f32x4 wr0 = *(const f32x4*)&wgt[k0],       wr1 = *(const f32x4*)&wgt[k0 + 4];
    f32x4 wd0 = *(const f32x4*)&wgt[256 + k0], wd1 = *(const f32x4*)&wgt[256 + k0 + 4];
    bf16x8 af;
#pragma unroll
    for (int j = 0; j < 4; j++)
      af[j] = (__bf16)silu_f((float)pvc[j] + (float)qvc[j] + rad * wr0[j] + dd0 * wd0[j]);
#pragma unroll
    for (int j = 0; j < 4; j++)
      af[4 + j] = (__bf16)silu_f((float)pvc[4 + j] + (float)qvc[4 + j] + rad * wr1[j] + dd0 * wd1[j]);
    // 16 MFMAs: all 256 output cols
    __builtin_amdgcn_s_setprio(1);
#pragma unroll
    for (int fn = 0; fn < 16; fn++) {
      int n = fn * 16 + l15;
      bf16x8 bf = *(const bf16x8*)&Bcur[n * 32 + ((kg ^ ((n >> 1) & 3)) << 3)];
      acc[fn] = __builtin_amdgcn_mfma_f32_16x16x32_bf16(af, bf, acc[fn], 0, 0, 0);
    }
    __builtin_amdgcn_s_setprio(0);
    if (t < 7) { pvc = pvn; qvc = qvn; }
    __syncthreads();   // drains DMA (vmcnt) + orders buffer swap
  }

  // ---- epilogue ----
  if (EPI == 0) {
    // per-wave LDS restage (2 passes x 8 rows) -> coalesced 16B row stores
    __bf16* ep = (__bf16*)(smem + 4096 + w * 4224);  // [8][264]
#pragma unroll
    for (int p = 0; p < 2; p++) {
      if ((kg >> 1) == p) {
        int rl = (kg & 1) * 4;
#pragma unroll
        for (int fn = 0; fn < 16; fn++) {
          int col = fn * 16 + l15;
          float bv = wgt[512 + col];
#pragma unroll
          for (int j = 0; j < 4; j++)
            ep[(rl + j) * 264 + col] = (__bf16)silu_f(acc[fn][j] + bv);
        }
      }
      __syncthreads();
#pragma unroll
      for (int i = 0; i < 4; i++) {
        int r = i * 2 + (lane >> 5);
        int g = lane & 31;
        uint4 v = *(const uint4*)&ep[r * 264 + g * 8];
        *(uint4*)(m2p + ((size_t)(R0 + w * 16 + p * 8 + r)) * 256 + g * 8) = v;
      }
      __syncthreads();
    }
  } else {
    float s[4] = {0.f, 0.f, 0.f, 0.f};
#pragma unroll
    for (int fn = 0; fn < 16; fn++) {
      int col = fn * 16 + l15;
      float bv = wgt[512 + col], wv = wgt[768 + col];
#pragma unroll
      for (int j = 0; j < 4; j++)
        s[j] += silu_f(acc[fn][j] + bv) * wv;
    }
#pragma unroll
    for (int off = 1; off < 16; off <<= 1)
#pragma unroll
      for (int j = 0; j < 4; j++)
        s[j] += __shfl_xor(s[j], off, 64);
    __syncthreads();
    if (l15 == 0) {
#pragma unroll
      for (int j = 0; j < 4; j++)
        reds[w * 16 + kg * 4 + j] = s[j];
    }
    __syncthreads();
    if (tid < 128) {
      float sv = reds[tid];
      size_t i = (size_t)R0 + tid;
      transp[i * 3 + 0] = cdp[i * 3 + 0] * sv;
      transp[i * 3 + 1] = cdp[i * 3 + 1] * sv;
      transp[i * 3 + 2] = cdp[i * 3 + 2] * sv;
    }
  }
}

// ---------------- 64x64 MFMA GEMM, 2-phase double-buffered ----------------
// C = epi(A[M,K] @ Bt[N,K]^T + bias).
// SPLIT=1: logical K=512, A-rows = [A(256) || A2(256)], both row-stride 256.
// EPI: 1 silu->bf16, 2 residual f32+=v & bf16 out, 5 bias+bf16
template <int EPI, int SPLIT>
__global__ __launch_bounds__(256) void k_gemm64(const __bf16* __restrict__ A, const __bf16* __restrict__ A2,
                                                const __bf16* __restrict__ Bt,
                                                const float* __restrict__ bias, __bf16* __restrict__ outb,
                                                float* __restrict__ outf, int M, int N, int K) {
  constexpr int BM = 64, BN = 64, BK = 64;
  __shared__ __bf16 As[2][BM * BK];
  __shared__ __bf16 Bs[2][BN * BK];
  const int tid = threadIdx.x;
  const int lane = tid & 63;
  const int wave = tid >> 6;
  const int wm = wave >> 1, wn = wave & 1;   // wave tile 32x32
  const size_t m0 = (size_t)blockIdx.x * BM;
  const size_t n0 = (size_t)blockIdx.y * BN;
  const int r0 = tid >> 3, g0 = tid & 7;
  const int gs0 = (g0 ^ (r0 & 7)) << 3;
  const int Astride = SPLIT ? 256 : K;

  f32x4 acc[2][2] = {};
  const int NT = K >> 6;

  {  // prologue: tile 0 (always from A)
    uint4 a0 = *(const uint4*)(A + (m0 + r0) * Astride + g0 * 8);
    uint4 a1 = *(const uint4*)(A + (m0 + r0 + 32) * Astride + g0 * 8);
    uint4 b0 = *(const uint4*)(Bt + (n0 + r0) * K + g0 * 8);
    uint4 b1 = *(const uint4*)(Bt + (n0 + r0 + 32) * K + g0 * 8);
    *(uint4*)&As[0][r0 * BK + gs0] = a0;
    *(uint4*)&As[0][(r0 + 32) * BK + gs0] = a1;
    *(uint4*)&Bs[0][r0 * BK + gs0] = b0;
    *(uint4*)&Bs[0][(r0 + 32) * BK + gs0] = b1;
  }
  __syncthreads();

  int buf = 0;
  for (int t = 0; t < NT; ++t) {
    const bool has = (t + 1 < NT);
    uint4 a0, a1, b0, b1;
    if (has) {
      int kt = (t + 1) << 6;
      const __bf16* Ab;
      int ko;
      if (SPLIT) { Ab = (kt < 256) ? A : A2; ko = kt & 255; }
      else       { Ab = A; ko = kt; }
      a0 = *(const uint4*)(Ab + (m0 + r0) * Astride + ko + g0 * 8);
      a1 = *(const uint4*)(Ab + (m0 + r0 + 32) * Astride + ko + g0 * 8);
      b0 = *(const uint4*)(Bt + (n0 + r0) * K + kt + g0 * 8);
      b1 = *(const uint4*)(Bt + (n0 + r0 + 32) * K + kt + g0 * 8);
    }
#pragma unroll
    for (int ks = 0; ks < BK; ks += 32) {
      const int kg = (ks >> 3) + (lane >> 4);
      bf16x8 af[2], bfv[2];
#pragma unroll
      for (int fm = 0; fm < 2; fm++) {
        int r = wm * 32 + fm * 16 + (lane & 15);
        af[fm] = *(const bf16x8*)&As[buf][r * BK + ((kg ^ (r & 7)) << 3)];
      }
#pragma unroll
      for (int fn = 0; fn < 2; fn++) {
        int r = wn * 32 + fn * 16 + (lane & 15);
        bfv[fn] = *(const bf16x8*)&Bs[buf][r * BK + ((kg ^ (r & 7)) << 3)];
      }
#pragma unroll
      for (int fm = 0; fm < 2; fm++)
#pragma unroll
        for (int fn = 0; fn < 2; fn++)
          acc[fm][fn] = __builtin_amdgcn_mfma_f32_16x16x32_bf16(af[fm], bfv[fn], acc[fm][fn], 0, 0, 0);
    }
    if (has) {
      *(uint4*)&As[buf ^ 1][r0 * BK + gs0] = a0;
      *(uint4*)&As[buf ^ 1][(r0 + 32) * BK + gs0] = a1;
      *(uint4*)&Bs[buf ^ 1][r0 * BK + gs0] = b0;
      *(uint4*)&Bs[buf ^ 1][(r0 + 32) * BK + gs0] = b1;
    }
    __syncthreads();
    buf ^= 1;
  }

#pragma unroll
  for (int fm = 0; fm < 2; fm++) {
#pragma unroll
    for (int fn = 0; fn < 2; fn++) {
      const size_t col = n0 + wn * 32 + fn * 16 + (lane & 15);
      float bv = bias[col];
#pragma unroll
      for (int j = 0; j < 4; j++) {
        size_t row = m0 + wm * 32 + fm * 16 + ((lane >> 4) << 2) + j;
        size_t idx = row * (size_t)N + col;
        float v = acc[fm][fn][j] + bv;
        if (EPI == 1) {
          outb[idx] = (__bf16)silu_f(v);
        } else if (EPI == 2) {
          float nh = outf[idx] + v;
          outf[idx] = nh;
          outb[idx] = (__bf16)nh;
        } else {
          outb[idx] = (__bf16)v;
        }
      }
    }
  }
}

// ---------------- host ----------------
extern "C" void kernel_launch(void* const* d_in, const int* in_sizes, int n_in,
                              void* d_out, int out_size, void* d_ws, size_t ws_size,
                              hipStream_t stream) {
  const float* h_in    = (const float*)d_in[0];
  const float* x_in    = (const float*)d_in[1];
  const int*   ei      = (const int*)d_in[2];
  const float* emb_w   = (const float*)d_in[3];
  const float* emb_b   = (const float*)d_in[4];
  const float* out_w   = (const float*)d_in[5];
  const float* out_b   = (const float*)d_in[6];
  const float* edge_w1 = (const float*)d_in[7];
  const float* edge_b1 = (const float*)d_in[8];
  const float* edge_w2 = (const float*)d_in[9];
  const float* edge_b2 = (const float*)d_in[10];
  const float* node_w1 = (const float*)d_in[11];
  const float* node_b1 = (const float*)d_in[12];
  const float* node_w2 = (const float*)d_in[13];
  const float* node_b2 = (const float*)d_in[14];
  const float* coord_w1 = (const float*)d_in[15];
  const float* coord_b1 = (const float*)d_in[16];
  const float* coord_w2 = (const float*)d_in[17];
  const float* coord_b2 = (const float*)d_in[18];
  const float* coord_w3 = (const float*)d_in[19];

  char* p = (char*)d_ws;
  auto alloc = [&](size_t bytes) -> void* {
    void* r = (void*)p;
    p += (bytes + 255) & ~(size_t)255;
    return r;
  };
  __bf16* e1T  = (__bf16*)alloc((size_t)6 * 512 * 256 * 2);
  __bf16* e2T  = (__bf16*)alloc((size_t)6 * 256 * 256 * 2);
  __bf16* n1T  = (__bf16*)alloc((size_t)6 * 256 * 512 * 2);
  __bf16* n2T  = (__bf16*)alloc((size_t)6 * 256 * 256 * 2);
  __bf16* c1T  = (__bf16*)alloc((size_t)3 * 512 * 256 * 2);
  __bf16* c2T  = (__bf16*)alloc((size_t)3 * 256 * 256 * 2);
  __bf16* h16  = (__bf16*)alloc((size_t)NN * HD * 2);
  __bf16* PQ16 = (__bf16*)alloc((size_t)NN * 512 * 2);
  __bf16* m2p  = (__bf16*)alloc((size_t)NE * HD * 2);
  __bf16* agg16 = (__bf16*)alloc((size_t)NN * HD * 2);
  __bf16* u    = (__bf16*)alloc((size_t)NN * HD * 2);
  float* hf    = (float*)alloc((size_t)NN * HD * 4);
  float* xc    = (float*)alloc((size_t)NN * 3 * 4);
  float* d0p   = (float*)alloc((size_t)NE * 4);
  float* radp  = (float*)alloc((size_t)NE * 4);
  float* cdp   = (float*)alloc((size_t)NE * 3 * 4);
  float* transp = (float*)alloc((size_t)NE * 3 * 4);
  float* bias512 = (float*)alloc((size_t)9 * 512 * 4);
  int* cnt     = (int*)alloc((size_t)NN * 4);
  int* offs    = (int*)alloc((size_t)(NN + 1) * 4);
  int* cursor  = (int*)alloc((size_t)NN * 4);
  int* elist   = (int*)alloc((size_t)NE * 4);
  int* rowp    = (int*)alloc((size_t)NE * 4);
  int* colp    = (int*)alloc((size_t)NE * 4);

  TJobs jobs;
  int nj = 0;
  for (int gi = 0; gi < 6; gi++) {
    jobs.j[nj++] = { edge_w1 + (size_t)gi * 514 * 256,             e1T + (size_t)gi * 512 * 256,             256, 256 };
    jobs.j[nj++] = { edge_w1 + (size_t)gi * 514 * 256 + 256 * 256, e1T + (size_t)gi * 512 * 256 + 256 * 256, 256, 256 };
    jobs.j[nj++] = { edge_w2 + (size_t)gi * 256 * 256,             e2T + (size_t)gi * 256 * 256,             256, 256 };
    jobs.j[nj++] = { node_w1 + (size_t)gi * 512 * 256,             n1T + (size_t)gi * 256 * 512,             512, 256 };
    jobs.j[nj++] = { node_w2 + (size_t)gi * 256 * 256,             n2T + (size_t)gi * 256 * 256,             256, 256 };
  }
  for (int b = 0; b < 3; b++) {
    jobs.j[nj++] = { coord_w1 + (size_t)b * 514 * 256,             c1T + (size_t)b * 512 * 256,              256, 256 };
    jobs.j[nj++] = { coord_w1 + (size_t)b * 514 * 256 + 256 * 256, c1T + (size_t)b * 512 * 256 + 256 * 256,  256, 256 };
    jobs.j[nj++] = { coord_w2 + (size_t)b * 256 * 256,             c2T + (size_t)b * 256 * 256,              256, 256 };
  }

  hipMemsetAsync(cnt, 0, (size_t)NN * 4, stream);
  k_transpose<<<dim3(16, 8, 39), 256, 0, stream>>>(jobs);
  k_hist<<<NE / 256, 256, 0, stream>>>(ei, cnt);
  k_scan<<<1, 1024, 0, stream>>>(cnt, offs, cursor);
  k_scatter<<<NE / 256, 256, 0, stream>>>(ei, cursor, elist);
  k_csrinit<<<NE / 256, 256, 0, stream>>>(elist, ei, x_in, rowp, colp, d0p, xc);
  k_mkbias<<<18, 256, 0, stream>>>(edge_b1, coord_b1, bias512);
  k_embed<<<NN, 256, 0, stream>>>(h_in, emb_w, emb_b, hf, h16);

  int gi = 0;
  for (int b = 0; b < 3; b++) {
    k_geo<<<NE / 256, 256, 0, stream>>>(rowp, colp, xc, radp, cdp);
    for (int s = 0; s < 2; s++, gi++) {
      const float* w1 = edge_w1 + (size_t)gi * 514 * 256;
      // PQ = h @ [W1a|W1b] + [b1|0]  -> bf16
      k_gemm64<5, 0><<<dim3(64, 8), 256, 0, stream>>>(
          h16, nullptr, e1T + (size_t)gi * 512 * 256, bias512 + gi * 512, PQ16, nullptr, NN, 512, 256);
      k_edgeblk<0><<<NE / 128, 512, 0, stream>>>(
          PQ16, rowp, colp, radp, d0p, w1 + 512 * 256, w1 + 513 * 256,
          e2T + (size_t)gi * 256 * 256, edge_b2 + gi * 256, m2p, nullptr, nullptr, nullptr);
      k_segsum<<<NN, 256, 0, stream>>>(m2p, offs, agg16);
      k_gemm64<1, 1><<<dim3(64, 4), 256, 0, stream>>>(
          h16, agg16, n1T + (size_t)gi * 256 * 512, node_b1 + gi * 256, u, nullptr, NN, 256, 512);
      k_gemm64<2, 0><<<dim3(64, 4), 256, 0, stream>>>(
          u, nullptr, n2T + (size_t)gi * 256 * 256, node_b2 + gi * 256, h16, hf, NN, 256, 256);
    }
    const float* w1c = coord_w1 + (size_t)b * 514 * 256;
    k_gemm64<5, 0><<<dim3(64, 8), 256, 0, stream>>>(
        h16, nullptr, c1T + (size_t)b * 512 * 256, bias512 + (6 + b) * 512, PQ16, nullptr, NN, 512, 256);
    k_edgeblk<1><<<NE / 128, 512, 0, stream>>>(
        PQ16, rowp, colp, radp, d0p, w1c + 512 * 256, w1c + 513 * 256,
        c2T + (size_t)b * 256 * 256, coord_b2 + b * 256, nullptr,
        coord_w3 + (size_t)b * 256, cdp, transp);
    k_xupd<<<NN / 256, 256, 0, stream>>>(transp, offs, xc);
  }
  k_out<<<256 + 48, 256, 0, stream>>>(hf, out_w, out_b, xc, (float*)d_out);
}